// Round 2
// baseline (453.386 us; speedup 1.0000x reference)
//
#include <hip/hip_runtime.h>

// Partial-CRF NLL: two forward scans (all-paths, constrained) + scalar diff.
//
// Math: new[j] = log sum_i exp(prev[i]) * E[i][j] + emit[t][j], E = exp(trans).
// State kept in scaled linear domain: P[j] = exp(prev[j] - logZ) in LDS,
// rescaled each step by v[1] (tag 1 always reachable -> v[1] > 0 always);
// logZ accumulated on thread 0. Forbidden transitions: exp(-1e5) == 0 exactly.
//
// Bool inputs (mask, uncertain_mask) may arrive as uint8 or int32 — detected
// on device: um[0,0,1] is True by construction, so um_bytes[1] == 1 iff uint8
// layout, == 0 iff little-endian int32 (byte 1 of element 0). Element i's
// 0/1 value is at byte (i << ushift) in either layout (LE LSB).
//
// Layout: grid = 1024 blocks = (batch b, scan) pairs; block = 256 threads.
// Thread (jj = tix>>2, q = tix&3) holds E^T rows {2jj, 2jj+1} over K-slice
// [28q, 28q+28) in registers. P broadcast from LDS via float4 (same-address
// broadcast: conflict-free). Partials combined with shfl_xor(1), shfl_xor(2).
// Two barriers per step. mask==0 steps skipped (uniform branch).

constexpr int B  = 512;
constexpr int T  = 512;
constexpr int L  = 102;
constexpr int LP = 112;            // padded L (pad entries are 0)
constexpr int START = L - 2;       // 100
constexpr int STOP  = L - 1;       // 101
constexpr int KQ = 28;             // K-slice width per q (4*28 = 112 = LP)

__global__ __launch_bounds__(256, 4)
void crf_fwd(const float* __restrict__ emit,
             const float* __restrict__ trans,
             const unsigned char* __restrict__ mask_b,
             const unsigned char* __restrict__ um_b,
             float* __restrict__ out)
{
  const int gold = blockIdx.x & 1;   // 0 = all-paths scan, 1 = constrained
  const int b    = blockIdx.x >> 1;

  const int tix = threadIdx.x;
  const int q   = tix & 3;
  const int jj  = tix >> 2;          // 0..63
  const int j0  = 2 * jj;
  const int j1  = 2 * jj + 1;
  const int jmine = 2 * jj + q;      // owned output tag (q < 2 only)
  const bool owner = (q < 2) && (jmine < L);

  // bool element stride: um[0,0,1] is always True -> byte 1 == 1 iff uint8.
  const int ushift = (um_b[1] != 0) ? 0 : 2;

  __shared__ __align__(16) float P[LP];
  __shared__ float s1s;
  __shared__ float wred[4];

  // E^T register slices: eta[c] = exp(trans[k][j0]), etb[c] = exp(trans[k][j1])
  float eta[KQ], etb[KQ];
#pragma unroll
  for (int c = 0; c < KQ; ++c) {
    const int k = KQ * q + c;
    eta[c] = (k < L && j0 < L) ? __expf(trans[k * L + j0]) : 0.0f;
    etb[c] = (k < L && j1 < L) ? __expf(trans[k * L + j1]) : 0.0f;
  }

  if (tix >= L && tix < LP) P[tix] = 0.0f;   // zero the pad once

  const float*         __restrict__ eb = emit + (size_t)b * T * L;
  const unsigned char* __restrict__ ub = um_b   + (((size_t)b * T * L) << ushift);
  const unsigned char* __restrict__ mb = mask_b + (((size_t)b * T)     << ushift);

  float logZ = 0.0f;

  // ---- t = 0 (mask[:,0] is always true) ----
  {
    float v = 0.0f;
    if (owner) {
      v = __expf(eb[jmine] + trans[START * L + jmine]);
      if (gold && !ub[(size_t)jmine << ushift]) v = 0.0f;
      if (jmine == 1) s1s = v;
    }
    __syncthreads();
    const float s1 = s1s;
    if (owner) P[jmine] = v * __builtin_amdgcn_rcpf(s1);
    logZ = __logf(s1);
    __syncthreads();
  }

  // prefetch t = 1
  float e_nxt = 0.0f;
  int u_nxt = 1;
  int m_nxt = mb[(size_t)1 << ushift];
  if (owner) {
    e_nxt = eb[L + jmine];
    if (gold) u_nxt = ub[(size_t)(L + jmine) << ushift];
  }

  for (int t = 1; t < T; ++t) {
    const float e_cur = e_nxt;
    const int u_cur = u_nxt;
    int m_cur = m_nxt;

    const int tn = (t + 1 < T) ? t + 1 : T - 1;   // clamped prefetch index
    if (owner) {
      e_nxt = eb[tn * L + jmine];
      if (gold) u_nxt = ub[(size_t)(tn * L + jmine) << ushift];
    }
    m_nxt = mb[(size_t)tn << ushift];

    m_cur = __builtin_amdgcn_readfirstlane(m_cur);
    if (!m_cur) continue;            // masked step: prev carried, skip all work

    // ---- dot: S[j] = sum_k P[k] * E[k][j] over my K-slice ----
    const float4* __restrict__ P4 =
        reinterpret_cast<const float4*>(P + KQ * q);   // 112*q bytes: aligned
    float a0 = 0.0f, a1 = 0.0f;
#pragma unroll
    for (int c4 = 0; c4 < 7; ++c4) {
      const float4 pv = P4[c4];
      a0 = fmaf(pv.x, eta[4 * c4 + 0], a0);
      a1 = fmaf(pv.x, etb[4 * c4 + 0], a1);
      a0 = fmaf(pv.y, eta[4 * c4 + 1], a0);
      a1 = fmaf(pv.y, etb[4 * c4 + 1], a1);
      a0 = fmaf(pv.z, eta[4 * c4 + 2], a0);
      a1 = fmaf(pv.z, etb[4 * c4 + 2], a1);
      a0 = fmaf(pv.w, eta[4 * c4 + 3], a0);
      a1 = fmaf(pv.w, etb[4 * c4 + 3], a1);
    }
    // combine K-slices (threads differing in q bits 0,1)
    a0 += __shfl_xor(a0, 1);  a0 += __shfl_xor(a0, 2);
    a1 += __shfl_xor(a1, 1);  a1 += __shfl_xor(a1, 2);

    float v = 0.0f;
    if (owner) {
      const float S = (q == 0) ? a0 : a1;
      v = S * __expf(e_cur);
      if (gold && !u_cur) v = 0.0f;  // tag j impossible here
      if (jmine == 1) s1s = v;       // rescale reference (always > 0)
    }
    __syncthreads();                 // dots done reading P; s1s visible
    const float s1 = s1s;
    if (owner) P[jmine] = v * __builtin_amdgcn_rcpf(s1);
    if (tix == 0) logZ += __logf(s1);
    __syncthreads();                 // new P visible
  }

  // ---- final: score = logZ + log sum_j P[j] * exp(trans[j][STOP]) ----
  float part = 0.0f;
  if (owner) part = P[jmine] * __expf(trans[jmine * L + STOP]);
  part += __shfl_xor(part, 1);
  part += __shfl_xor(part, 2);
  part += __shfl_xor(part, 4);
  part += __shfl_xor(part, 8);
  part += __shfl_xor(part, 16);
  part += __shfl_xor(part, 32);
  if ((tix & 63) == 0) wred[tix >> 6] = part;
  __syncthreads();
  if (tix == 0) {
    const float tot = wred[0] + wred[1] + wred[2] + wred[3];
    const float score = logZ + __logf(tot);
    atomicAdd(out, gold ? -score : score);
  }
}

extern "C" void kernel_launch(void* const* d_in, const int* in_sizes, int n_in,
                              void* d_out, int out_size, void* d_ws, size_t ws_size,
                              hipStream_t stream) {
  const float*         emit = (const float*)d_in[0];
  const float*         trn  = (const float*)d_in[1];
  const unsigned char* msk  = (const unsigned char*)d_in[2];  // bool: u8 or i32
  const unsigned char* umk  = (const unsigned char*)d_in[3];  // bool: u8 or i32
  float* out = (float*)d_out;

  hipMemsetAsync(d_out, 0, sizeof(float), stream);
  crf_fwd<<<dim3(2 * B), dim3(256), 0, stream>>>(emit, trn, msk, umk, out);
}